// Round 2
// baseline (26762.341 us; speedup 1.0000x reference)
//
#include <hip/hip_runtime.h>
#include <stdint.h>

#define LSEQ  512
#define VOCAB 32000
#define GCOLS 3072               // 3*H2 per direction
#define WHH_STRIDE 1032          // 1024 + 8 halfs pad (16B)

typedef __attribute__((ext_vector_type(8))) short short8;
typedef __attribute__((ext_vector_type(4))) float f32x4;
typedef unsigned short u16;
typedef unsigned int   u32;

__device__ __forceinline__ float b2f(u16 u) {
  union { u32 i; float f; } x; x.i = ((u32)u) << 16; return x.f;
}
__device__ __forceinline__ u16 f2b(float f) {
  union { float f; u32 i; } x; x.f = f;
  u32 r = (x.i + 0x7fffu + ((x.i >> 16) & 1u)) >> 16;
  return (u16)r;
}
__device__ __forceinline__ void load_lds16(const void* g, void* l) {
  __builtin_amdgcn_global_load_lds(
      (const __attribute__((address_space(1))) void*)g,
      (__attribute__((address_space(3))) void*)l, 16, 0, 0);
}
__device__ __forceinline__ float sigmoidf_(float x) {
  return __builtin_amdgcn_rcpf(1.f + __expf(-x));
}
__device__ __forceinline__ float tanhf_(float x) {
  x = fminf(fmaxf(x, -30.f), 30.f);
  float e = __expf(2.f * x);
  return (e - 1.f) * __builtin_amdgcn_rcpf(e + 1.f);
}

// ---------------------------------------------------------------------------
// Phase 0: f32 -> bf16 (RNE) bulk conversion into workspace.
// ---------------------------------------------------------------------------
__global__ __launch_bounds__(256) void k_cvt(const float* __restrict__ s,
                                             u16* __restrict__ d, int n) {
  int i = (blockIdx.x * 256 + threadIdx.x) * 4;
  if (i >= n) return;
  float4 v = *(const float4*)(s + i);
  u32 lo = (u32)f2b(v.x) | ((u32)f2b(v.y) << 16);
  u32 hi = (u32)f2b(v.z) | ((u32)f2b(v.w) << 16);
  uint2 pk; pk.x = lo; pk.y = hi;
  *(uint2*)(d + i) = pk;
}

// ---------------------------------------------------------------------------
// Phase 1: E'[v, g] = sum_k emb[v,k] * Wih[g,k] + bih[g]  (both dirs, bf16 in,
// f32 acc + f32 bias, bf16 out). Grid: 48 gate-tiles x 250 vocab-tiles.
// ---------------------------------------------------------------------------
__global__ __launch_bounds__(256) void k_gx(
    const u16* __restrict__ emb,
    const u16* __restrict__ Wf, const float* __restrict__ bf,
    const u16* __restrict__ Wr, const float* __restrict__ br,
    u16* __restrict__ Ef, u16* __restrict__ Er)
{
  __shared__ u16 lA[128 * 64];   // Wih tile  [gatecol 128][k 64]
  __shared__ u16 lB[128 * 64];   // emb tile  [vocab 128][k 64]
  const int bid = blockIdx.x;
  const int mt = bid % 48;
  const int nt = bid / 48;
  const u16*   W    = (mt < 24) ? Wf : Wr;
  const float* bias = (mt < 24) ? bf : br;
  u16*         Eo   = (mt < 24) ? Ef : Er;
  const int m0 = (mt < 24 ? mt : mt - 24) * 128;
  const int n0 = nt * 128;
  const int tid = threadIdx.x;
  const int lane = tid & 63, wv = tid >> 6;
  const int wA = wv & 1, wB = wv >> 1;
  const int lm = lane & 15, lk = lane >> 4;

  f32x4 acc[4][4];
#pragma unroll
  for (int i = 0; i < 4; ++i)
#pragma unroll
    for (int j = 0; j < 4; ++j) acc[i][j] = (f32x4){0.f, 0.f, 0.f, 0.f};

  for (int k0 = 0; k0 < 1024; k0 += 64) {
#pragma unroll
    for (int it = 0; it < 4; ++it) {
      int slot = it * 256 + tid;         // 0..1023
      int row = slot >> 3, seg = slot & 7;
      load_lds16(W + (size_t)(m0 + row) * 1024 + k0 + seg * 8,
                 lA + (size_t)(it * 256 + wv * 64) * 8);
      load_lds16(emb + (size_t)(n0 + row) * 1024 + k0 + seg * 8,
                 lB + (size_t)(it * 256 + wv * 64) * 8);
    }
    __syncthreads();
#pragma unroll
    for (int kc = 0; kc < 2; ++kc) {
      short8 af[4], bfr[4];
#pragma unroll
      for (int i = 0; i < 4; ++i)
        af[i] = *(const short8*)&lA[(64 * wA + 16 * i + lm) * 64 + kc * 32 + lk * 8];
#pragma unroll
      for (int j = 0; j < 4; ++j)
        bfr[j] = *(const short8*)&lB[(64 * wB + 16 * j + lm) * 64 + kc * 32 + lk * 8];
#pragma unroll
      for (int i = 0; i < 4; ++i)
#pragma unroll
        for (int j = 0; j < 4; ++j)
          acc[i][j] = __builtin_amdgcn_mfma_f32_16x16x32_bf16(af[i], bfr[j], acc[i][j], 0, 0, 0);
    }
    __syncthreads();
  }

#pragma unroll
  for (int i = 0; i < 4; ++i) {
    int gcol0 = m0 + 64 * wA + 16 * i + lk * 4;
    const float* bp = bias + gcol0;
    float b0 = bp[0], b1 = bp[1], b2_ = bp[2], b3 = bp[3];
#pragma unroll
    for (int j = 0; j < 4; ++j) {
      int vrow = n0 + 64 * wB + 16 * j + lm;
      f32x4 v = acc[i][j];
      u32 lo = (u32)f2b(v.x + b0) | ((u32)f2b(v.y + b1) << 16);
      u32 hi = (u32)f2b(v.z + b2_) | ((u32)f2b(v.w + b3) << 16);
      uint2 pk; pk.x = lo; pk.y = hi;
      *(uint2*)(Eo + (size_t)vrow * GCOLS + gcol0) = pk;
    }
  }
}

// ---------------------------------------------------------------------------
// Phase 2: persistent GRU recurrence, both directions in lockstep.
// 256 WGs x 256 thr. bid -> d(bit0), batch-group g(bit1), column-WG cw(>>2).
// WG owns 16 hidden cols of dir d for 64 batch rows. Whh slice in LDS;
// gates r,z fragments register-cached (256 VGPR). h fp32 in regs (own cols),
// bf16 broadcast via ping-pong global buffer; one 64-WG agent-scope barrier
// per step (4 independent groups, padded counters).
// reference's x[:, ::-1] reverses BATCH => rev GRU reads seq[127-b].
// ---------------------------------------------------------------------------
__global__ __launch_bounds__(256, 1) void k_rnn(
    const int* __restrict__ seq,
    const u16* __restrict__ Ef, const u16* __restrict__ Er,
    const u16* __restrict__ Whf, const float* __restrict__ bhf,
    const u16* __restrict__ Whr, const float* __restrict__ bhr,
    u16* __restrict__ hbuf, int* __restrict__ bars,
    float* __restrict__ out)
{
  extern __shared__ u16 lds[];
  u16* whh = lds;                           // [48][WHH_STRIDE]
  u16* gx  = lds + 48 * WHH_STRIDE;         // [64][64]
  const int bid = blockIdx.x;
  const int d = bid & 1, g = (bid >> 1) & 1, cw = bid >> 2;
  const int c0 = cw * 16;
  const int barid = (bid & 3) * 32;         // 128B-separated counters
  const u16*   Wh = d ? Whr : Whf;
  const float* bh = d ? bhr : bhf;
  const u16*   E  = d ? Er  : Ef;
  const int tid = threadIdx.x;
  const int lane = tid & 63, wv = tid >> 6;
  const int lm = lane & 15, lk = lane >> 4;

  // --- stage Whh slice: LDS row gate*16+jc  <-  Wh[gate*1024 + c0 + jc][:]
  for (int it = 0; it < 24; ++it) {
    int idx = it * 256 + tid;              // 0..6143
    int row = idx >> 7, q = idx & 127;
    int gate = row >> 4, jc = row & 15;
    uint4 v = *(const uint4*)(Wh + (size_t)((gate << 10) + c0 + jc) * 1024 + q * 8);
    *(uint4*)(whh + (size_t)row * WHH_STRIDE + q * 8) = v;
  }
  const float bhrv = bh[c0 + lm];
  const float bhzv = bh[1024 + c0 + lm];
  const float bhnv = bh[2048 + c0 + lm];

  float hprev[4] = {0.f, 0.f, 0.f, 0.f};
  const int rowA = g * 64 + wv * 16 + lm;
  const int hbase = d * 128;

  const int sr_r = tid / 3;                // gx staging: threads 0..191
  const int sr_s = tid - sr_r * 3;
  const int sr_b = g * 64 + sr_r;
  const int sr_seqrow = d ? (127 - sr_b) : sr_b;

  __syncthreads();   // whh ready

  // --- register-cache r & z gate fragments (rows lm and 16+lm)
  short8 w0[32], w1[32];
  {
    const u16* p0 = whh + (size_t)lm * WHH_STRIDE + lk * 8;
    const u16* p1 = whh + (size_t)(16 + lm) * WHH_STRIDE + lk * 8;
#pragma unroll
    for (int kc = 0; kc < 32; ++kc) {
      w0[kc] = *(const short8*)(p0 + kc * 32);
      w1[kc] = *(const short8*)(p1 + kc * 32);
    }
  }
  const u16* pn = whh + (size_t)(32 + lm) * WHH_STRIDE + lk * 8;

  for (int t = 0; t < LSEQ; ++t) {
    // ---- stage gx tile: gx[r][gate*16 + 0..15] = E'[tok][gate*1024+c0 ..+15]
    if (tid < 192) {
      int tok = seq[sr_seqrow * LSEQ + t];
      const u16* src = E + (size_t)tok * GCOLS + sr_s * 1024 + c0;
      uint4 v0 = *(const uint4*)src;
      uint4 v1 = *(const uint4*)(src + 8);
      *(uint4*)(gx + sr_r * 64 + sr_s * 16) = v0;
      *(uint4*)(gx + sr_r * 64 + sr_s * 16 + 8) = v1;
    }
    __syncthreads();

    // ---- gh = h @ Whh_slice^T
    f32x4 a0 = (f32x4){0.f,0.f,0.f,0.f};
    f32x4 a1 = (f32x4){0.f,0.f,0.f,0.f};
    f32x4 a2 = (f32x4){0.f,0.f,0.f,0.f};
    const u16* hb = hbuf + ((size_t)((t & 1) * 256 + hbase + rowA)) * 1024 + lk * 8;
#pragma unroll
    for (int kc = 0; kc < 32; ++kc) {
      short8 av  = *(const short8*)(hb + kc * 32);
      short8 bnv = *(const short8*)(pn + kc * 32);
      a0 = __builtin_amdgcn_mfma_f32_16x16x32_bf16(av, w0[kc], a0, 0, 0, 0);
      a1 = __builtin_amdgcn_mfma_f32_16x16x32_bf16(av, w1[kc], a1, 0, 0, 0);
      a2 = __builtin_amdgcn_mfma_f32_16x16x32_bf16(av, bnv,    a2, 0, 0, 0);
    }

    // ---- gates + state update (C layout: col=c0+lm, row=lk*4+i)
    u16* hnext = hbuf + ((size_t)(((t + 1) & 1) * 256 + hbase)) * 1024;
#pragma unroll
    for (int i = 0; i < 4; ++i) {
      int grow = wv * 16 + lk * 4 + i;
      float gxr = b2f(gx[grow * 64 + lm]);
      float gxz = b2f(gx[grow * 64 + 16 + lm]);
      float gxn = b2f(gx[grow * 64 + 32 + lm]);
      float rg = sigmoidf_(gxr + a0[i] + bhrv);
      float zg = sigmoidf_(gxz + a1[i] + bhzv);
      float ng = tanhf_(gxn + rg * (a2[i] + bhnv));
      float hn = (1.f - zg) * ng + zg * hprev[i];
      hprev[i] = hn;
      hnext[(size_t)(g * 64 + grow) * 1024 + c0 + lm] = f2b(hn);
    }

    // ---- 64-WG barrier for this (d,g) group
    __threadfence();   // release: write back my h-stores for cross-XCD readers
    __syncthreads();
    if (tid == 0) {
      __hip_atomic_fetch_add(&bars[barid], 1, __ATOMIC_RELEASE, __HIP_MEMORY_SCOPE_AGENT);
      const int tgt = (t + 1) * 64;
      while (__hip_atomic_load(&bars[barid], __ATOMIC_RELAXED, __HIP_MEMORY_SCOPE_AGENT) < tgt) {
        __builtin_amdgcn_s_sleep(2);
      }
    }
    __syncthreads();
    __threadfence();   // acquire: invalidate stale lines before reading fresh h
  }

  // ---- final output: out[0, b, d*1024 + c]  (f32)
#pragma unroll
  for (int i = 0; i < 4; ++i) {
    int b = g * 64 + wv * 16 + lk * 4 + i;
    out[(size_t)b * 2048 + d * 1024 + c0 + lm] = hprev[i];
  }
}

extern "C" void kernel_launch(void* const* d_in, const int* in_sizes, int n_in,
                              void* d_out, int out_size, void* d_ws, size_t ws_size,
                              hipStream_t stream)
{
  const int*   seq  = (const int*)d_in[0];
  const float* emb  = (const float*)d_in[1];
  const float* Wihf = (const float*)d_in[2];
  const float* Whhf = (const float*)d_in[3];
  const float* bihf = (const float*)d_in[4];
  const float* bhhf = (const float*)d_in[5];
  const float* Wihr = (const float*)d_in[6];
  const float* Whhr = (const float*)d_in[7];
  const float* bihr = (const float*)d_in[8];
  const float* bhhr = (const float*)d_in[9];
  float* out = (float*)d_out;

  // workspace layout (u16 units)
  u16* ws = (u16*)d_ws;
  const size_t nE = (size_t)VOCAB * GCOLS;          // 98,304,000 per dir
  const size_t nEmb = (size_t)VOCAB * 1024;         // 32,768,000
  const size_t nW = (size_t)GCOLS * 1024;           // 3,145,728
  size_t off = 0;
  u16* Ef     = ws + off; off += nE;
  u16* Er     = ws + off; off += nE;
  u16* emb_b  = ws + off; off += nEmb;
  u16* Wihf_b = ws + off; off += nW;
  u16* Wihr_b = ws + off; off += nW;
  u16* Whhf_b = ws + off; off += nW;
  u16* Whhr_b = ws + off; off += nW;
  u16* hbuf   = ws + off; off += (size_t)2 * 256 * 1024;
  int* bars   = (int*)(ws + off);

  hipMemsetAsync(hbuf, 0, (size_t)2 * 256 * 1024 * sizeof(u16) + 512, stream);

  // Phase 0: f32 -> bf16 copies
  k_cvt<<<dim3((nEmb / 4 + 255) / 256), dim3(256), 0, stream>>>(emb,  emb_b,  (int)nEmb);
  k_cvt<<<dim3((nW   / 4 + 255) / 256), dim3(256), 0, stream>>>(Wihf, Wihf_b, (int)nW);
  k_cvt<<<dim3((nW   / 4 + 255) / 256), dim3(256), 0, stream>>>(Wihr, Wihr_b, (int)nW);
  k_cvt<<<dim3((nW   / 4 + 255) / 256), dim3(256), 0, stream>>>(Whhf, Whhf_b, (int)nW);
  k_cvt<<<dim3((nW   / 4 + 255) / 256), dim3(256), 0, stream>>>(Whhr, Whhr_b, (int)nW);

  // Phase 1: vocab-level input projection tables
  k_gx<<<dim3(48 * 250), dim3(256), 0, stream>>>(emb_b, Wihf_b, bihf, Wihr_b, bihr, Ef, Er);

  // Phase 2: persistent recurrence (1 WG/CU, 256 WGs)
  const int smem = (48 * WHH_STRIDE + 64 * 64) * sizeof(u16);   // 107,264 B
  hipFuncSetAttribute(reinterpret_cast<const void*>(k_rnn),
                      hipFuncAttributeMaxDynamicSharedMemorySize, smem);
  k_rnn<<<dim3(256), dim3(256), smem, stream>>>(seq, Ef, Er, Whhf_b, bhhf, Whhr_b, bhhr,
                                                hbuf, bars, out);
}

// Round 3
// 6205.506 us; speedup vs baseline: 4.3127x; 4.3127x over previous
//
#include <hip/hip_runtime.h>
#include <stdint.h>

#define LSEQ  512
#define VOCAB 32000
#define GCOLS 3072               // 3*H2 per direction
#define WHH_STRIDE 1032          // 1024 + 8 halfs pad (16B)

typedef __attribute__((ext_vector_type(8))) short short8;
typedef __attribute__((ext_vector_type(4))) float f32x4;
typedef unsigned short u16;
typedef unsigned int   u32;
typedef unsigned long long u64;

__device__ __forceinline__ float b2f(u16 u) {
  union { u32 i; float f; } x; x.i = ((u32)u) << 16; return x.f;
}
__device__ __forceinline__ u16 f2b(float f) {
  union { float f; u32 i; } x; x.f = f;
  u32 r = (x.i + 0x7fffu + ((x.i >> 16) & 1u)) >> 16;
  return (u16)r;
}
__device__ __forceinline__ void load_lds16(const void* g, void* l) {
  __builtin_amdgcn_global_load_lds(
      (const __attribute__((address_space(1))) void*)g,
      (__attribute__((address_space(3))) void*)l, 16, 0, 0);
}
__device__ __forceinline__ float sigmoidf_(float x) {
  return __builtin_amdgcn_rcpf(1.f + __expf(-x));
}
__device__ __forceinline__ float tanhf_(float x) {
  x = fminf(fmaxf(x, -30.f), 30.f);
  float e = __expf(2.f * x);
  return (e - 1.f) * __builtin_amdgcn_rcpf(e + 1.f);
}

// ---------------------------------------------------------------------------
// Phase 0: f32 -> bf16 (RNE) bulk conversion into workspace.
// ---------------------------------------------------------------------------
__global__ __launch_bounds__(256) void k_cvt(const float* __restrict__ s,
                                             u16* __restrict__ d, int n) {
  int i = (blockIdx.x * 256 + threadIdx.x) * 4;
  if (i >= n) return;
  float4 v = *(const float4*)(s + i);
  u32 lo = (u32)f2b(v.x) | ((u32)f2b(v.y) << 16);
  u32 hi = (u32)f2b(v.z) | ((u32)f2b(v.w) << 16);
  uint2 pk; pk.x = lo; pk.y = hi;
  *(uint2*)(d + i) = pk;
}

// ---------------------------------------------------------------------------
// Phase 1: E'[v, g] = sum_k emb[v,k] * Wih[g,k] + bih[g]  (both dirs).
// Unchanged from R2 (verified correct).
// ---------------------------------------------------------------------------
__global__ __launch_bounds__(256) void k_gx(
    const u16* __restrict__ emb,
    const u16* __restrict__ Wf, const float* __restrict__ bf,
    const u16* __restrict__ Wr, const float* __restrict__ br,
    u16* __restrict__ Ef, u16* __restrict__ Er)
{
  __shared__ u16 lA[128 * 64];
  __shared__ u16 lB[128 * 64];
  const int bid = blockIdx.x;
  const int mt = bid % 48;
  const int nt = bid / 48;
  const u16*   W    = (mt < 24) ? Wf : Wr;
  const float* bias = (mt < 24) ? bf : br;
  u16*         Eo   = (mt < 24) ? Ef : Er;
  const int m0 = (mt < 24 ? mt : mt - 24) * 128;
  const int n0 = nt * 128;
  const int tid = threadIdx.x;
  const int lane = tid & 63, wv = tid >> 6;
  const int wA = wv & 1, wB = wv >> 1;
  const int lm = lane & 15, lk = lane >> 4;

  f32x4 acc[4][4];
#pragma unroll
  for (int i = 0; i < 4; ++i)
#pragma unroll
    for (int j = 0; j < 4; ++j) acc[i][j] = (f32x4){0.f, 0.f, 0.f, 0.f};

  for (int k0 = 0; k0 < 1024; k0 += 64) {
#pragma unroll
    for (int it = 0; it < 4; ++it) {
      int slot = it * 256 + tid;
      int row = slot >> 3, seg = slot & 7;
      load_lds16(W + (size_t)(m0 + row) * 1024 + k0 + seg * 8,
                 lA + (size_t)(it * 256 + wv * 64) * 8);
      load_lds16(emb + (size_t)(n0 + row) * 1024 + k0 + seg * 8,
                 lB + (size_t)(it * 256 + wv * 64) * 8);
    }
    __syncthreads();
#pragma unroll
    for (int kc = 0; kc < 2; ++kc) {
      short8 af[4], bfr[4];
#pragma unroll
      for (int i = 0; i < 4; ++i)
        af[i] = *(const short8*)&lA[(64 * wA + 16 * i + lm) * 64 + kc * 32 + lk * 8];
#pragma unroll
      for (int j = 0; j < 4; ++j)
        bfr[j] = *(const short8*)&lB[(64 * wB + 16 * j + lm) * 64 + kc * 32 + lk * 8];
#pragma unroll
      for (int i = 0; i < 4; ++i)
#pragma unroll
        for (int j = 0; j < 4; ++j)
          acc[i][j] = __builtin_amdgcn_mfma_f32_16x16x32_bf16(af[i], bfr[j], acc[i][j], 0, 0, 0);
    }
    __syncthreads();
  }

#pragma unroll
  for (int i = 0; i < 4; ++i) {
    int gcol0 = m0 + 64 * wA + 16 * i + lk * 4;
    const float* bp = bias + gcol0;
    float b0 = bp[0], b1 = bp[1], b2_ = bp[2], b3 = bp[3];
#pragma unroll
    for (int j = 0; j < 4; ++j) {
      int vrow = n0 + 64 * wB + 16 * j + lm;
      f32x4 v = acc[i][j];
      u32 lo = (u32)f2b(v.x + b0) | ((u32)f2b(v.y + b1) << 16);
      u32 hi = (u32)f2b(v.z + b2_) | ((u32)f2b(v.w + b3) << 16);
      uint2 pk; pk.x = lo; pk.y = hi;
      *(uint2*)(Eo + (size_t)vrow * GCOLS + gcol0) = pk;
    }
  }
}

// ---------------------------------------------------------------------------
// Phase 2: persistent GRU recurrence. Zero cache-maintenance design:
//  - h stores: relaxed agent-scope atomic u16 (write-through to IF; no dirty
//    L2 => no buffer_wbl2 on release; __syncthreads' vmcnt(0) drains them)
//  - h loads:  relaxed agent-scope atomic u64 (bypass L1/L2, always-fresh
//    from IF => no acquire fence, ping-pong D=2 is safe)
//  - barrier:  relaxed agent add + relaxed agent spin load (as R2)
//  - gx double-buffered in LDS; E(t+1) prefetched into regs at top of step.
// ---------------------------------------------------------------------------
__global__ __launch_bounds__(256, 1) void k_rnn(
    const int* __restrict__ seq,
    const u16* __restrict__ Ef, const u16* __restrict__ Er,
    const u16* __restrict__ Whf, const float* __restrict__ bhf,
    const u16* __restrict__ Whr, const float* __restrict__ bhr,
    u16* __restrict__ hbuf, int* __restrict__ bars,
    float* __restrict__ out)
{
  extern __shared__ u16 lds[];
  u16* whh = lds;                           // [48][WHH_STRIDE]
  u16* gx  = lds + 48 * WHH_STRIDE;         // [2][64][64] double buffer
  const int bid = blockIdx.x;
  const int d = bid & 1, g = (bid >> 1) & 1, cw = bid >> 2;
  const int c0 = cw * 16;
  const int barid = (bid & 3) * 32;         // 128B-separated counters
  const u16*   Wh = d ? Whr : Whf;
  const float* bh = d ? bhr : bhf;
  const u16*   E  = d ? Er  : Ef;
  const int tid = threadIdx.x;
  const int lane = tid & 63, wv = tid >> 6;
  const int lm = lane & 15, lk = lane >> 4;

  // --- stage Whh slice: LDS row gate*16+jc <- Wh[gate*1024 + c0 + jc][:]
  for (int it = 0; it < 24; ++it) {
    int idx = it * 256 + tid;
    int row = idx >> 7, q = idx & 127;
    int gate = row >> 4, jc = row & 15;
    uint4 v = *(const uint4*)(Wh + (size_t)((gate << 10) + c0 + jc) * 1024 + q * 8);
    *(uint4*)(whh + (size_t)row * WHH_STRIDE + q * 8) = v;
  }
  const float bhrv = bh[c0 + lm];
  const float bhzv = bh[1024 + c0 + lm];
  const float bhnv = bh[2048 + c0 + lm];

  float hprev[4] = {0.f, 0.f, 0.f, 0.f};
  const int rowA = g * 64 + wv * 16 + lm;

  const int sr_r = tid / 3;                 // gx staging: threads 0..191
  const int sr_s = tid - sr_r * 3;
  const int sr_b = g * 64 + sr_r;
  const int sr_seqrow = d ? (127 - sr_b) : sr_b;
  const bool stager = (tid < 192);

  // prime gx(0) into buffer 0
  if (stager) {
    int tok = seq[sr_seqrow * LSEQ + 0];
    const u16* src = E + (size_t)tok * GCOLS + sr_s * 1024 + c0;
    uint4 v0 = *(const uint4*)src;
    uint4 v1 = *(const uint4*)(src + 8);
    *(uint4*)(gx + sr_r * 64 + sr_s * 16) = v0;
    *(uint4*)(gx + sr_r * 64 + sr_s * 16 + 8) = v1;
  }
  __syncthreads();   // whh + gx(0) ready

  const u16* whp0 = whh + (size_t)lm * WHH_STRIDE + lk * 8;
  const u16* whp1 = whh + (size_t)(16 + lm) * WHH_STRIDE + lk * 8;
  const u16* whp2 = whh + (size_t)(32 + lm) * WHH_STRIDE + lk * 8;

  for (int t = 0; t < LSEQ; ++t) {
    // ---- prefetch E(t+1) into regs (latency overlaps h-loads + MFMA)
    uint4 pf0, pf1;
    const bool havepf = stager && (t + 1 < LSEQ);
    if (havepf) {
      int tok = seq[sr_seqrow * LSEQ + t + 1];
      const u16* src = E + (size_t)tok * GCOLS + sr_s * 1024 + c0;
      pf0 = *(const uint4*)src;
      pf1 = *(const uint4*)(src + 8);
    }

    // ---- h(t) loads: agent-scope relaxed atomics (IF-fresh, no fence)
    u16* hb = hbuf + ((size_t)((t & 1) * 256 + d * 128 + rowA)) * 1024 + lk * 8;
    u64 hq[64];
#pragma unroll
    for (int kc = 0; kc < 32; ++kc) {
      hq[2 * kc]     = __hip_atomic_load((u64*)(hb + kc * 32),     __ATOMIC_RELAXED, __HIP_MEMORY_SCOPE_AGENT);
      hq[2 * kc + 1] = __hip_atomic_load((u64*)(hb + kc * 32 + 4), __ATOMIC_RELAXED, __HIP_MEMORY_SCOPE_AGENT);
    }

    // ---- gh = h @ Whh_slice^T
    f32x4 a0 = (f32x4){0.f,0.f,0.f,0.f};
    f32x4 a1 = (f32x4){0.f,0.f,0.f,0.f};
    f32x4 a2 = (f32x4){0.f,0.f,0.f,0.f};
#pragma unroll
    for (int kc = 0; kc < 32; ++kc) {
      union { u64 q[2]; short8 s; } u;
      u.q[0] = hq[2 * kc]; u.q[1] = hq[2 * kc + 1];
      short8 av  = u.s;
      short8 b0v = *(const short8*)(whp0 + kc * 32);
      short8 b1v = *(const short8*)(whp1 + kc * 32);
      short8 b2v = *(const short8*)(whp2 + kc * 32);
      a0 = __builtin_amdgcn_mfma_f32_16x16x32_bf16(av, b0v, a0, 0, 0, 0);
      a1 = __builtin_amdgcn_mfma_f32_16x16x32_bf16(av, b1v, a1, 0, 0, 0);
      a2 = __builtin_amdgcn_mfma_f32_16x16x32_bf16(av, b2v, a2, 0, 0, 0);
    }

    // ---- gates + state update (C layout: col=c0+lm, row=lk*4+i)
    const u16* gxr_ = gx + (t & 1) * 4096;
    u16* hnext = hbuf + ((size_t)(((t + 1) & 1) * 256 + d * 128 + g * 64)) * 1024;
#pragma unroll
    for (int i = 0; i < 4; ++i) {
      int grow = wv * 16 + lk * 4 + i;
      float gxr = b2f(gxr_[grow * 64 + lm]);
      float gxz = b2f(gxr_[grow * 64 + 16 + lm]);
      float gxn = b2f(gxr_[grow * 64 + 32 + lm]);
      float rg = sigmoidf_(gxr + a0[i] + bhrv);
      float zg = sigmoidf_(gxz + a1[i] + bhzv);
      float ng = tanhf_(gxn + rg * (a2[i] + bhnv));
      float hn = (1.f - zg) * ng + zg * hprev[i];
      hprev[i] = hn;
      // write-through store to IF (no dirty L2 anywhere)
      __hip_atomic_store(&hnext[(size_t)grow * 1024 + c0 + lm], f2b(hn),
                         __ATOMIC_RELAXED, __HIP_MEMORY_SCOPE_AGENT);
    }

    // ---- stage gx(t+1) into the other LDS buffer
    if (havepf) {
      u16* gxw = gx + ((t + 1) & 1) * 4096;
      *(uint4*)(gxw + sr_r * 64 + sr_s * 16) = pf0;
      *(uint4*)(gxw + sr_r * 64 + sr_s * 16 + 8) = pf1;
    }

    // ---- 64-WG barrier (syncthreads drains vmcnt => h stores are at IF)
    __syncthreads();
    if (tid == 0) {
      __hip_atomic_fetch_add(&bars[barid], 1, __ATOMIC_RELAXED, __HIP_MEMORY_SCOPE_AGENT);
      const int tgt = (t + 1) * 64;
      while (__hip_atomic_load(&bars[barid], __ATOMIC_RELAXED, __HIP_MEMORY_SCOPE_AGENT) < tgt) {
        __builtin_amdgcn_s_sleep(1);
      }
    }
    __syncthreads();
  }

  // ---- final output: out[0, b, d*1024 + c]  (f32)
#pragma unroll
  for (int i = 0; i < 4; ++i) {
    int b = g * 64 + wv * 16 + lk * 4 + i;
    out[(size_t)b * 2048 + d * 1024 + c0 + lm] = hprev[i];
  }
}

extern "C" void kernel_launch(void* const* d_in, const int* in_sizes, int n_in,
                              void* d_out, int out_size, void* d_ws, size_t ws_size,
                              hipStream_t stream)
{
  const int*   seq  = (const int*)d_in[0];
  const float* emb  = (const float*)d_in[1];
  const float* Wihf = (const float*)d_in[2];
  const float* Whhf = (const float*)d_in[3];
  const float* bihf = (const float*)d_in[4];
  const float* bhhf = (const float*)d_in[5];
  const float* Wihr = (const float*)d_in[6];
  const float* Whhr = (const float*)d_in[7];
  const float* bihr = (const float*)d_in[8];
  const float* bhhr = (const float*)d_in[9];
  float* out = (float*)d_out;

  // workspace layout (u16 units)
  u16* ws = (u16*)d_ws;
  const size_t nE = (size_t)VOCAB * GCOLS;
  const size_t nEmb = (size_t)VOCAB * 1024;
  const size_t nW = (size_t)GCOLS * 1024;
  size_t off = 0;
  u16* Ef     = ws + off; off += nE;
  u16* Er     = ws + off; off += nE;
  u16* emb_b  = ws + off; off += nEmb;
  u16* Wihf_b = ws + off; off += nW;
  u16* Wihr_b = ws + off; off += nW;
  u16* Whhf_b = ws + off; off += nW;
  u16* Whhr_b = ws + off; off += nW;
  u16* hbuf   = ws + off; off += (size_t)2 * 256 * 1024;
  int* bars   = (int*)(ws + off);

  hipMemsetAsync(hbuf, 0, (size_t)2 * 256 * 1024 * sizeof(u16) + 512, stream);

  // Phase 0: f32 -> bf16 copies
  k_cvt<<<dim3((nEmb / 4 + 255) / 256), dim3(256), 0, stream>>>(emb,  emb_b,  (int)nEmb);
  k_cvt<<<dim3((nW   / 4 + 255) / 256), dim3(256), 0, stream>>>(Wihf, Wihf_b, (int)nW);
  k_cvt<<<dim3((nW   / 4 + 255) / 256), dim3(256), 0, stream>>>(Wihr, Wihr_b, (int)nW);
  k_cvt<<<dim3((nW   / 4 + 255) / 256), dim3(256), 0, stream>>>(Whhf, Whhf_b, (int)nW);
  k_cvt<<<dim3((nW   / 4 + 255) / 256), dim3(256), 0, stream>>>(Whhr, Whhr_b, (int)nW);

  // Phase 1: vocab-level input projection tables
  k_gx<<<dim3(48 * 250), dim3(256), 0, stream>>>(emb_b, Wihf_b, bihf, Wihr_b, bihr, Ef, Er);

  // Phase 2: persistent recurrence (1 WG/CU, 256 WGs)
  const int smem = (48 * WHH_STRIDE + 2 * 64 * 64) * sizeof(u16);   // 115,456 B
  hipFuncSetAttribute(reinterpret_cast<const void*>(k_rnn),
                      hipFuncAttributeMaxDynamicSharedMemorySize, smem);
  k_rnn<<<dim3(256), dim3(256), smem, stream>>>(seq, Ef, Er, Whhf_b, bhhf, Whhr_b, bhhr,
                                                hbuf, bars, out);
}